// Round 11
// baseline (1320.973 us; speedup 1.0000x reference)
//
#include <hip/hip_runtime.h>

// LIF layer: I = spikes @ W^T + b (fp32), then sequential fp32 LIF scan.
//
// NUMERICS CONTRACT (proven in round 2, absmax=0): each output element of the
// GEMM must be a strictly sequential ascending-k fmaf chain from 0.0f over
// k=0..1023, followed by exactly one fp32 bias add. The scan must be the exact
// op sequence t=v/20 (IEEE div); u=I-t; v=v+u; s=(v>1); v=s?0:v.
// Any blocking change must preserve the per-element rounding sequence.
//
// Round 11: R3/R5/R10 all plateau at 69% VALUBusy; R6-R9 at 58%. Unifying
// model: ds_read_b128 ~12 cyc on the LDS pipe -> 8x8 tile needs 192 LDS-cyc
// per 128 FMA-cyc (ceiling 67%, measured 69%); 16x8 fixes the ratio but its
// ~250-reg footprint starves issue (58%). No schedule change alters the LDS
// instruction count -- so REMOVE one operand from LDS: A-fragment reads are
// 16-lane broadcasts (4 distinct addrs/wave) -> load A directly from global
// through L1 on the VMEM pipe (8 float2 per thread per 2-k slab; 8KB/block
// /tile, single-fetch, L1-resident). W keeps the proven swizzled dbuf LDS.
// LDS demand falls to ~84% of FMA cycles -> no longer binding. Register
// budget: acc 64 (AGPR) + a2 16 + lw 8 + addrs ~ 115 -> 4 waves/SIMD.

constexpr int kT   = 100;
constexpr int kB   = 256;
constexpr int kIn  = 1024;
constexpr int kOut = 1024;
constexpr int kM   = kT * kB;          // 25600 GEMM rows

constexpr int BM = 128;
constexpr int BN = 128;
constexpr int BK = 16;
constexpr int NT = kIn / BK;           // 64 k-tiles

// ---------------------------------------------------------------------------
// GEMM: I[M,kOut] = A[M,kIn] * W^T[kOut,kIn] + bias   (fp32, sequential-k FMA)
// 256 threads = 16(tr) x 16(tc); micro-tile 8 rows x 8 cols per thread.
// A: direct from global (VMEM/L1). W: swizzled double-buffered LDS.
// ---------------------------------------------------------------------------
__global__ __launch_bounds__(256, 4)
void gemm_f32(const float* __restrict__ A,
              const float* __restrict__ W,
              const float* __restrict__ bias,
              float* __restrict__ I)
{
    __shared__ float Ws[2][BK * BN];   // 2 x 8 KB, 16B chunk c at slot c^(c>>2)

    const int tid = threadIdx.x;
    const int m0  = blockIdx.y * BM;
    const int n0  = blockIdx.x * BN;

    const int tc = tid & 15;       // cols tc*8 .. +7
    const int tr = tid >> 4;       // rows tr*8 .. +7

    // W-fragment read slots (chunk c stored at c^(c>>2))
    const int pw0 = (((2 * tc    ) ^ ((2 * tc    ) >> 2)) & 31) * 4;
    const int pw1 = (((2 * tc + 1) ^ ((2 * tc + 1) >> 2)) & 31) * 4;

    // W staging: thread owns row sr = tid>>1 (0..127), k-half sc0 = (tid&1)*8
    const int sr  = tid >> 1;
    const int sc0 = (tid & 1) * 8;
    const float* Wrow = W + (size_t)(n0 + sr) * kIn + sc0;
    const int wslot = ((((sr >> 2) ^ (sr >> 4)) & 31) * 4) + (sr & 3);

    // A base for this thread's 8 rows (m0 + tr*8 + j), j = 0..7
    const float* Abase = A + (size_t)(m0 + tr * 8) * kIn;

    float4 lw0 = *reinterpret_cast<const float4*>(Wrow);
    float4 lw1 = *reinterpret_cast<const float4*>(Wrow + 4);

    float acc[8][8];
#pragma unroll
    for (int j = 0; j < 8; ++j)
#pragma unroll
        for (int l = 0; l < 8; ++l) acc[j][l] = 0.0f;

    for (int t = 0; t < NT; ++t) {
        float* Wb = Ws[t & 1];

        // stage current W regs into this tile's buffer (2-way writes, free)
        {
            const float* p0 = reinterpret_cast<const float*>(&lw0);
            const float* p1 = reinterpret_cast<const float*>(&lw1);
#pragma unroll
            for (int kk = 0; kk < 4; ++kk) {
                Wb[(sc0 + kk)     * BN + wslot] = p0[kk];
                Wb[(sc0 + 4 + kk) * BN + wslot] = p1[kk];
            }
        }

        __syncthreads();   // single barrier per tile (race-free: R7 argument)

        // prefetch next tile's W after the barrier (drains under FMA phase)
        if (t + 1 < NT) {
            lw0 = *reinterpret_cast<const float4*>(Wrow + (t + 1) * BK);
            lw1 = *reinterpret_cast<const float4*>(Wrow + (t + 1) * BK + 4);
        }

        // 8 slabs of 2 k each; A loaded per slab directly from global (L1).
        // k strictly ascending => per-element chain order preserved.
#pragma unroll
        for (int p = 0; p < 8; ++p) {
            const int k2 = t * BK + 2 * p;
            float2 a2[8];
#pragma unroll
            for (int j = 0; j < 8; ++j)
                a2[j] = *reinterpret_cast<const float2*>(Abase + (size_t)j * kIn + k2);

#pragma unroll
            for (int kk = 0; kk < 2; ++kk) {
                const int k = 2 * p + kk;
                const float4 w0 = *reinterpret_cast<const float4*>(&Wb[k * BN + pw0]);
                const float4 w1 = *reinterpret_cast<const float4*>(&Wb[k * BN + pw1]);
                const float w[8] = {w0.x, w0.y, w0.z, w0.w, w1.x, w1.y, w1.z, w1.w};
#pragma unroll
                for (int j = 0; j < 8; ++j) {
                    const float aj = kk ? a2[j].y : a2[j].x;
#pragma unroll
                    for (int l = 0; l < 8; ++l)
                        acc[j][l] = fmaf(aj, w[l], acc[j][l]);
                }
            }
        }
        // no trailing barrier: next iter writes the OTHER Ws buffer
    }

    // epilogue: single fp32 bias add per element, float4 stores
#pragma unroll
    for (int j = 0; j < 8; ++j) {
        const int m = m0 + tr * 8 + j;
#pragma unroll
        for (int h = 0; h < 2; ++h) {
            const int n = n0 + tc * 8 + h * 4;
            float4 o4;
            o4.x = acc[j][h * 4 + 0] + bias[n + 0];
            o4.y = acc[j][h * 4 + 1] + bias[n + 1];
            o4.z = acc[j][h * 4 + 2] + bias[n + 2];
            o4.w = acc[j][h * 4 + 3] + bias[n + 3];
            *reinterpret_cast<float4*>(&I[(size_t)m * kOut + n]) = o4;
        }
    }
}

// ---------------------------------------------------------------------------
// LIF scan (fp32, exact op order), 4 elements per thread (float4 I/O):
//   t1 = v / 20; u = I - t1; v = v + u; s = v > 1; v = s ? 0 : v
// Iin may alias out (per-thread read-before-write on identical addresses).
// ---------------------------------------------------------------------------
__global__ __launch_bounds__(256)
void lif_scan_f32(const float* Iin, float* out)
{
    const int idx4 = (blockIdx.x * blockDim.x + threadIdx.x) * 4;
    if (idx4 >= kB * kOut) return;

    float v0 = 0.0f, v1 = 0.0f, v2 = 0.0f, v3 = 0.0f;
    for (int t = 0; t < kT; ++t) {
        const size_t off = (size_t)t * (kB * kOut) + idx4;
        const float4 Iv = *reinterpret_cast<const float4*>(&Iin[off]);
        float4 s4;

        { const float t1 = v0 / 20.0f; const float u = Iv.x - t1; v0 = v0 + u;
          const bool s = (v0 > 1.0f); s4.x = s ? 1.0f : 0.0f; if (s) v0 = 0.0f; }
        { const float t1 = v1 / 20.0f; const float u = Iv.y - t1; v1 = v1 + u;
          const bool s = (v1 > 1.0f); s4.y = s ? 1.0f : 0.0f; if (s) v1 = 0.0f; }
        { const float t1 = v2 / 20.0f; const float u = Iv.z - t1; v2 = v2 + u;
          const bool s = (v2 > 1.0f); s4.z = s ? 1.0f : 0.0f; if (s) v2 = 0.0f; }
        { const float t1 = v3 / 20.0f; const float u = Iv.w - t1; v3 = v3 + u;
          const bool s = (v3 > 1.0f); s4.w = s ? 1.0f : 0.0f; if (s) v3 = 0.0f; }

        *reinterpret_cast<float4*>(&out[off]) = s4;
    }
}

extern "C" void kernel_launch(void* const* d_in, const int* in_sizes, int n_in,
                              void* d_out, int out_size, void* d_ws, size_t ws_size,
                              hipStream_t stream) {
    const float* spikes = (const float*)d_in[0];   // [T, B, IN] fp32
    const float* W      = (const float*)d_in[1];   // [OUT, IN] fp32
    const float* bias   = (const float*)d_in[2];   // [OUT] fp32
    float* out = (float*)d_out;                    // [T, B, OUT] fp32 spikes

    const size_t iBytes = (size_t)kM * kOut * sizeof(float);   // 104.9 MB
    dim3 grid(kOut / BN, kM / BM);                 // 8 x 200 = 1600 blocks

    float* Ibuf = (ws_size >= iBytes && d_ws != nullptr) ? (float*)d_ws : out;
    gemm_f32<<<grid, 256, 0, stream>>>(spikes, W, bias, Ibuf);
    lif_scan_f32<<<(kB * kOut) / (256 * 4), 256, 0, stream>>>(Ibuf, out);
}